// Round 8
// baseline (195.747 us; speedup 1.0000x reference)
//
#include <hip/hip_runtime.h>

// ECE/MCE: softmax-confidence calibration histogram.
// logits f32 [N=131072, C=1000], labels int32 [N] -> out f32 [2] = (ece, mce).
//
// Per row: conf = 1/sum(exp(x - max)), pred = argmax(x) (first occurrence),
// bin = clip(ceil(conf*10)-1, 0, 9); accumulate (cnt, conf_sum, acc_sum).
//
// R8 = R5 (best: 103.0 us — two-pass register-resident row, 1-row prefetch,
// NON-TEMPORAL loads [R7 proved nt = +8%], block-adjacent interleave: block
// owns 64 consecutive rows, waves take rbeg+w+4i) + FUSED EPILOGUE: the last
// block to finish (device-scope ticket) computes ece/mce in-kernel, removing
// the second dispatch. g_acc re-read via atomicAdd(p,0.0f) (RMW at the
// device-coherent point — safe under per-XCD L2 non-coherence, G16).

constexpr int N_BINS = 10;
constexpr int NCOLS  = 1000;
constexpr int NV4    = NCOLS / 4;   // 250 float4 per row
constexpr int BLOCK  = 256;         // 4 waves/block
constexpr int GRID   = 2048;        // 64 rows per block exactly

using f4 = __attribute__((ext_vector_type(4))) float;

__device__ __forceinline__ void load_row(const float* __restrict__ logits,
                                         int row, int lane,
                                         f4& x0, f4& x1, f4& x2, f4& x3)
{
    const f4* rp = reinterpret_cast<const f4*>(logits + (size_t)row * NCOLS);
    x0 = __builtin_nontemporal_load(rp + lane);
    x1 = __builtin_nontemporal_load(rp + lane + 64);
    x2 = __builtin_nontemporal_load(rp + lane + 128);
    if (lane + 192 < NV4) {                  // lanes 0..57; exec-masked, no OOB
        x3 = __builtin_nontemporal_load(rp + lane + 192);
    } else {
        x3 = (f4){-INFINITY, -INFINITY, -INFINITY, -INFINITY};
    }
}

__global__ __launch_bounds__(BLOCK) void ece_rows_kernel(
    const float* __restrict__ logits,
    const int*   __restrict__ labels,
    float*       __restrict__ g_acc,    // [3*N_BINS]: cnt | conf_sum | acc_sum
    unsigned int* __restrict__ g_ticket,
    float*       __restrict__ out,      // [2]: ece, mce
    int nrows)
{
    __shared__ float s_bins[BLOCK / 64][3][N_BINS];
    __shared__ unsigned int s_rank;

    const int tid  = threadIdx.x;
    const int wave = tid >> 6;
    const int lane = tid & 63;

    for (int i = tid; i < (BLOCK / 64) * 3 * N_BINS; i += BLOCK)
        (&s_bins[0][0][0])[i] = 0.0f;
    __syncthreads();

    // block owns a contiguous run of rows; waves interleave stride-4 within it
    const int rpb  = (nrows + GRID - 1) / GRID;         // rows per block (=64)
    const int rbeg = blockIdx.x * rpb;
    const int rend = min(rbeg + rpb, nrows);

    f4 a0, a1, a2, a3;
    int row = rbeg + wave;
    if (row < rend) load_row(logits, row, lane, a0, a1, a2, a3);

    while (row < rend) {
        const int nxt = row + (BLOCK / 64);  // wave-uniform, stride 4
        const int lab = labels[row];         // issued early

        // prefetch next row (hidden under this row's processing)
        f4 b0, b1, b2, b3;
        if (nxt < rend) load_row(logits, nxt, lane, b0, b1, b2, b3);

        // ---- per-lane max + first-occurrence argmax over 16 values ----
        float maxv = -INFINITY;
        int   maxi = 0x7fffffff;
        {
            int base = 4 * lane;
            #define UPD(val, idx) if ((val) > maxv) { maxv = (val); maxi = (idx); }
            UPD(a0.x, base)       UPD(a0.y, base + 1)   UPD(a0.z, base + 2)   UPD(a0.w, base + 3)
            base = 4 * (lane + 64);
            UPD(a1.x, base)       UPD(a1.y, base + 1)   UPD(a1.z, base + 2)   UPD(a1.w, base + 3)
            base = 4 * (lane + 128);
            UPD(a2.x, base)       UPD(a2.y, base + 1)   UPD(a2.z, base + 2)   UPD(a2.w, base + 3)
            base = 4 * (lane + 192);
            UPD(a3.x, base)       UPD(a3.y, base + 1)   UPD(a3.z, base + 2)   UPD(a3.w, base + 3)
            #undef UPD
        }

        // wave-wide (max, argmax) butterfly; ties -> smaller index
        #pragma unroll
        for (int off = 32; off > 0; off >>= 1) {
            float ov = __shfl_xor(maxv, off);
            int   oi = __shfl_xor(maxi, off);
            if (ov > maxv || (ov == maxv && oi < maxi)) { maxv = ov; maxi = oi; }
        }

        // ---- sum of exp(x - max); -INF pads give exp(-inf)=0 ----
        float s = __expf(a0.x - maxv) + __expf(a0.y - maxv)
                + __expf(a0.z - maxv) + __expf(a0.w - maxv)
                + __expf(a1.x - maxv) + __expf(a1.y - maxv)
                + __expf(a1.z - maxv) + __expf(a1.w - maxv)
                + __expf(a2.x - maxv) + __expf(a2.y - maxv)
                + __expf(a2.z - maxv) + __expf(a2.w - maxv)
                + __expf(a3.x - maxv) + __expf(a3.y - maxv)
                + __expf(a3.z - maxv) + __expf(a3.w - maxv);
        #pragma unroll
        for (int off = 32; off > 0; off >>= 1)
            s += __shfl_xor(s, off);

        if (lane == 0) {
            float conf = 1.0f / s;                   // exp(0)/sum == max softmax
            float acc  = (maxi == lab) ? 1.0f : 0.0f;
            int b = (int)ceilf(conf * (float)N_BINS) - 1;
            b = min(max(b, 0), N_BINS - 1);
            s_bins[wave][0][b] += 1.0f;              // lane-0-private slots
            s_bins[wave][1][b] += conf;
            s_bins[wave][2][b] += acc;
        }

        a0 = b0; a1 = b1; a2 = b2; a3 = b3;
        row = nxt;
    }

    __syncthreads();
    // combine this block's waves, one atomic per (component, bin) per block
    if (tid < 3 * N_BINS) {
        int c = tid / N_BINS;
        int b = tid % N_BINS;
        float t = 0.0f;
        #pragma unroll
        for (int w = 0; w < BLOCK / 64; ++w) t += s_bins[w][c][b];
        if (t != 0.0f) atomicAdd(&g_acc[c * N_BINS + b], t);
    }

    // ---- fused epilogue: last block to pass here computes ece/mce ----
    // __syncthreads drains vmcnt -> this block's g_acc atomics are complete
    // at the device-coherent point before the ticket increment.
    __syncthreads();
    if (tid == 0) {
        __threadfence();
        s_rank = atomicAdd(g_ticket, 1u);
    }
    __syncthreads();
    if (s_rank == (unsigned int)(gridDim.x - 1) && tid == 0) {
        const float inv_n = 1.0f / (float)nrows;
        float ece = 0.0f, mce = 0.0f;
        for (int b = 0; b < N_BINS; ++b) {
            // atomic RMW read: true device-coherent values (per-XCD L2 safe)
            float cnt = atomicAdd(&g_acc[b], 0.0f);
            float cs  = atomicAdd(&g_acc[N_BINS + b], 0.0f);
            float as  = atomicAdd(&g_acc[2 * N_BINS + b], 0.0f);
            if (cnt > 0.0f) {
                float gap = fabsf((cs - as) / cnt);
                ece += gap * cnt * inv_n;
                mce  = fmaxf(mce, gap);
            }
        }
        out[0] = ece;
        out[1] = mce;
    }
}

extern "C" void kernel_launch(void* const* d_in, const int* in_sizes, int n_in,
                              void* d_out, int out_size, void* d_ws, size_t ws_size,
                              hipStream_t stream)
{
    const float* logits = (const float*)d_in[0];
    const int*   labels = (const int*)d_in[1];
    const int    nrows  = in_sizes[1];

    // ws layout: float g_acc[30] | uint ticket
    float*        g_acc    = (float*)d_ws;
    unsigned int* g_ticket = (unsigned int*)((char*)d_ws + 3 * N_BINS * sizeof(float));
    hipMemsetAsync(d_ws, 0, 3 * N_BINS * sizeof(float) + sizeof(unsigned int), stream);

    ece_rows_kernel<<<GRID, BLOCK, 0, stream>>>(logits, labels, g_acc, g_ticket,
                                                (float*)d_out, nrows);
}

// Round 9
// 102.941 us; speedup vs baseline: 1.9015x; 1.9015x over previous
//
#include <hip/hip_runtime.h>

// ECE/MCE: softmax-confidence calibration histogram.
// logits f32 [N=131072, C=1000], labels int32 [N] -> out f32 [2] = (ece, mce).
//
// Per row: conf = 1/sum(exp(x - max)), pred = argmax(x) (first occurrence),
// bin = clip(ceil(conf*10)-1, 0, 9); accumulate (cnt, conf_sum, acc_sum).
//
// FINAL = R5, the measured best (103.0 us ~ 5.4 TB/s effective read).
// A/B ledger: block-adjacent schedule 103.0 beats chunked 103.6 / strided
// 108.9; nt loads beat normal (110.9); register prefetch beats LDS staging
// (118.2); separate tiny final dispatch beats fused last-block epilogue
// (195.7 -- threadfence + grid-serialized tail). Two-pass register-resident
// row, 1-row software prefetch, wave-butterfly (max,argmax) + exp-sum.

constexpr int N_BINS = 10;
constexpr int NCOLS  = 1000;
constexpr int NV4    = NCOLS / 4;   // 250 float4 per row
constexpr int BLOCK  = 256;         // 4 waves/block
constexpr int GRID   = 2048;        // 64 rows per block exactly

using f4 = __attribute__((ext_vector_type(4))) float;

__device__ __forceinline__ void load_row(const float* __restrict__ logits,
                                         int row, int lane,
                                         f4& x0, f4& x1, f4& x2, f4& x3)
{
    const f4* rp = reinterpret_cast<const f4*>(logits + (size_t)row * NCOLS);
    x0 = __builtin_nontemporal_load(rp + lane);
    x1 = __builtin_nontemporal_load(rp + lane + 64);
    x2 = __builtin_nontemporal_load(rp + lane + 128);
    if (lane + 192 < NV4) {                  // lanes 0..57; exec-masked, no OOB
        x3 = __builtin_nontemporal_load(rp + lane + 192);
    } else {
        x3 = (f4){-INFINITY, -INFINITY, -INFINITY, -INFINITY};
    }
}

__global__ __launch_bounds__(BLOCK) void ece_rows_kernel(
    const float* __restrict__ logits,
    const int*   __restrict__ labels,
    float*       __restrict__ g_acc,   // [3*N_BINS]: cnt | conf_sum | acc_sum
    int nrows)
{
    __shared__ float s_bins[BLOCK / 64][3][N_BINS];

    const int wave = threadIdx.x >> 6;
    const int lane = threadIdx.x & 63;

    for (int i = threadIdx.x; i < (BLOCK / 64) * 3 * N_BINS; i += BLOCK)
        (&s_bins[0][0][0])[i] = 0.0f;
    __syncthreads();

    // block owns a contiguous run of rows; waves interleave stride-4 within it
    const int rpb  = (nrows + GRID - 1) / GRID;         // rows per block (=64)
    const int rbeg = blockIdx.x * rpb;
    const int rend = min(rbeg + rpb, nrows);

    f4 a0, a1, a2, a3;
    int row = rbeg + wave;
    if (row < rend) load_row(logits, row, lane, a0, a1, a2, a3);

    while (row < rend) {
        const int nxt = row + (BLOCK / 64);  // wave-uniform, stride 4
        const int lab = labels[row];         // issued early

        // prefetch next row (hidden under this row's processing)
        f4 b0, b1, b2, b3;
        if (nxt < rend) load_row(logits, nxt, lane, b0, b1, b2, b3);

        // ---- per-lane max + first-occurrence argmax over 16 values ----
        float maxv = -INFINITY;
        int   maxi = 0x7fffffff;
        {
            int base = 4 * lane;
            #define UPD(val, idx) if ((val) > maxv) { maxv = (val); maxi = (idx); }
            UPD(a0.x, base)       UPD(a0.y, base + 1)   UPD(a0.z, base + 2)   UPD(a0.w, base + 3)
            base = 4 * (lane + 64);
            UPD(a1.x, base)       UPD(a1.y, base + 1)   UPD(a1.z, base + 2)   UPD(a1.w, base + 3)
            base = 4 * (lane + 128);
            UPD(a2.x, base)       UPD(a2.y, base + 1)   UPD(a2.z, base + 2)   UPD(a2.w, base + 3)
            base = 4 * (lane + 192);
            UPD(a3.x, base)       UPD(a3.y, base + 1)   UPD(a3.z, base + 2)   UPD(a3.w, base + 3)
            #undef UPD
        }

        // wave-wide (max, argmax) butterfly; ties -> smaller index
        #pragma unroll
        for (int off = 32; off > 0; off >>= 1) {
            float ov = __shfl_xor(maxv, off);
            int   oi = __shfl_xor(maxi, off);
            if (ov > maxv || (ov == maxv && oi < maxi)) { maxv = ov; maxi = oi; }
        }

        // ---- sum of exp(x - max); -INF pads give exp(-inf)=0 ----
        float s = __expf(a0.x - maxv) + __expf(a0.y - maxv)
                + __expf(a0.z - maxv) + __expf(a0.w - maxv)
                + __expf(a1.x - maxv) + __expf(a1.y - maxv)
                + __expf(a1.z - maxv) + __expf(a1.w - maxv)
                + __expf(a2.x - maxv) + __expf(a2.y - maxv)
                + __expf(a2.z - maxv) + __expf(a2.w - maxv)
                + __expf(a3.x - maxv) + __expf(a3.y - maxv)
                + __expf(a3.z - maxv) + __expf(a3.w - maxv);
        #pragma unroll
        for (int off = 32; off > 0; off >>= 1)
            s += __shfl_xor(s, off);

        if (lane == 0) {
            float conf = 1.0f / s;                   // exp(0)/sum == max softmax
            float acc  = (maxi == lab) ? 1.0f : 0.0f;
            int b = (int)ceilf(conf * (float)N_BINS) - 1;
            b = min(max(b, 0), N_BINS - 1);
            s_bins[wave][0][b] += 1.0f;              // lane-0-private slots
            s_bins[wave][1][b] += conf;
            s_bins[wave][2][b] += acc;
        }

        a0 = b0; a1 = b1; a2 = b2; a3 = b3;
        row = nxt;
    }

    __syncthreads();
    // combine this block's waves, one atomic per (component, bin) per block
    if (threadIdx.x < 3 * N_BINS) {
        int c = threadIdx.x / N_BINS;
        int b = threadIdx.x % N_BINS;
        float t = 0.0f;
        #pragma unroll
        for (int w = 0; w < BLOCK / 64; ++w) t += s_bins[w][c][b];
        if (t != 0.0f) atomicAdd(&g_acc[c * N_BINS + b], t);
    }
}

__global__ void ece_final_kernel(const float* __restrict__ g_acc,
                                 float* __restrict__ out, float inv_n)
{
    if (threadIdx.x == 0) {
        float ece = 0.0f, mce = 0.0f;
        for (int b = 0; b < N_BINS; ++b) {
            float cnt = g_acc[b];
            float cs  = g_acc[N_BINS + b];
            float as  = g_acc[2 * N_BINS + b];
            if (cnt > 0.0f) {
                float gap = fabsf((cs - as) / cnt);
                ece += gap * cnt * inv_n;
                mce  = fmaxf(mce, gap);
            }
        }
        out[0] = ece;
        out[1] = mce;
    }
}

extern "C" void kernel_launch(void* const* d_in, const int* in_sizes, int n_in,
                              void* d_out, int out_size, void* d_ws, size_t ws_size,
                              hipStream_t stream)
{
    const float* logits = (const float*)d_in[0];
    const int*   labels = (const int*)d_in[1];
    const int    nrows  = in_sizes[1];

    float* g_acc = (float*)d_ws;
    hipMemsetAsync(d_ws, 0, 3 * N_BINS * sizeof(float), stream);

    ece_rows_kernel<<<GRID, BLOCK, 0, stream>>>(logits, labels, g_acc, nrows);
    ece_final_kernel<<<1, 64, 0, stream>>>(g_acc, (float*)d_out, 1.0f / (float)nrows);
}